// Round 5
// baseline (13290.782 us; speedup 1.0000x reference)
//
#include <hip/hip_runtime.h>
#include <hip/hip_fp16.h>
#include <stdint.h>

// ---------------------------------------------------------------------------
// GPT forward, MI355X. Round 5: attention rewrite.
//  - Round 4 passed (absmax 0.0156, 12.3 ms). rocprof: 48 attn dispatches
//    (NC=8 x 6 layers) x 180 us = 8.6 ms = 70% of runtime. Cause: 160
//    floats/thread vs VGPR_Count=68 -> scratch spills (WRITE_SIZE 24.5 MB vs
//    12.6 MB pure output), occupancy 17.8%, lane divergence.
//  - New attn: thread=(seq,h,t,d-half) -> ~90 live VGPRs, no spill; wave =
//    one (seq,head); dot via __shfl_xor(partial,1); causal mask via -1e30
//    scores (exp->0 exactly, uniform flow); wave-uniform K/V loads; uint4
//    load/store with 1-op bf16->f32 unpack.
// GEMMs (working, m92-style) untouched this round.
// ---------------------------------------------------------------------------

typedef unsigned short u16;
typedef __bf16 bf16x8 __attribute__((ext_vector_type(8)));
typedef float f32x4 __attribute__((ext_vector_type(4)));

#define M_TOK 131072   // B*T
#define CDIM  384
#define TT    32
#define HH    6
#define DHEAD 64
#define LLAY  6
#define VOCAB 80
#define FFDIM 1536
#define QKVN  1152

__device__ __forceinline__ float b2f(u16 v) {
    union { unsigned int u; float f; } x; x.u = ((unsigned int)v) << 16; return x.f;
}
__device__ __forceinline__ u16 f2b(float f) {
    union { float f; unsigned int u; } x; x.f = f;
    unsigned int r = (x.u + 0x7fffu + ((x.u >> 16) & 1u)) >> 16;   // RNE
    return (u16)r;
}
// unpack 8 bf16 (uint4) -> 8 fp32; 1 VALU op per element
__device__ __forceinline__ void unpack8(uint4 v, float* f) {
    const unsigned w[4] = {v.x, v.y, v.z, v.w};
#pragma unroll
    for (int j = 0; j < 4; j++) {
        union { unsigned u; float f; } a, b;
        a.u = w[j] << 16;
        b.u = w[j] & 0xffff0000u;
        f[2 * j]     = a.f;
        f[2 * j + 1] = b.f;
    }
}
// mode: 0 = fp32, 1 = bf16, 2 = fp16
__device__ __forceinline__ float load_in(const void* p, size_t i, int m) {
    if (m == 0) return ((const float*)p)[i];
    u16 v = ((const u16*)p)[i];
    if (m == 1) return b2f(v);
    __half h; *(u16*)&h = v; return __half2float(h);
}

// --------------------------- dtype detection -------------------------------
__global__ void detect_dtype_kernel(const void* ln1g, int* flag) {
    if (threadIdx.x == 0 && blockIdx.x == 0) {
        unsigned w = *(const unsigned*)ln1g;       // ln1_g is all 1.0
        int m = 0;
        if (w == 0x3F803F80u) m = 1;               // bf16 ones
        else if (w == 0x3C003C00u) m = 2;          // fp16 ones
        *flag = m;
    }
}

// --------------------------- param convert ---------------------------------
__global__ void cvt_kernel(const void* __restrict__ src, u16* __restrict__ dst,
                           unsigned n, const int* __restrict__ flag) {
    const int m = *flag;
    unsigned i = blockIdx.x * 256 + threadIdx.x;
    if (i < n) dst[i] = f2b(load_in(src, i, m));
}

// --------------------------- weight repack ---------------------------------
// dst [L][Cc][R] = src [L][R][Cc] transposed per layer (B^T layout for GEMM)
__global__ void transpose_kernel(const void* __restrict__ src, u16* __restrict__ dst,
                                 int R, int Cc, unsigned total,
                                 const int* __restrict__ flag) {
    const int m = *flag;
    unsigned i = blockIdx.x * 256 + threadIdx.x;
    if (i >= total) return;
    unsigned c  = i % R;
    unsigned t2 = i / R;
    unsigned n  = t2 % Cc;
    unsigned l  = t2 / Cc;
    dst[i] = f2b(load_in(src, ((size_t)l * R + c) * Cc + n, m));
}

// dst[l][n][c] (n in [0,1152)): n<384 -> Wq[l][n>>6][c][n&63]; then Wk; then Wv
__global__ void pack_qkv_kernel(const void* __restrict__ Wq, const void* __restrict__ Wk,
                                const void* __restrict__ Wv, u16* __restrict__ dst,
                                const int* __restrict__ flag) {
    const int m = *flag;
    unsigned i = blockIdx.x * 256 + threadIdx.x;
    const unsigned total = (unsigned)LLAY * QKVN * CDIM;
    if (i >= total) return;
    unsigned c  = i % CDIM;
    unsigned t2 = i / CDIM;
    unsigned n  = t2 % QKVN;
    unsigned l  = t2 / QKVN;
    const void* W = (n < 384) ? Wq : (n < 768) ? Wk : Wv;
    unsigned nn = n % 384;
    unsigned hh = nn >> 6, d = nn & 63;
    dst[i] = f2b(load_in(W, (((size_t)l * HH + hh) * CDIM + c) * DHEAD + d, m));
}

// ------------------------------- embedding ---------------------------------
__global__ void embed_kernel(const int* __restrict__ idx, const void* __restrict__ tok,
                             const void* __restrict__ pos, float* __restrict__ x,
                             unsigned rows0, const int* __restrict__ flag) {
    const int m = *flag;
    unsigned i = blockIdx.x * 256 + threadIdx.x;
    unsigned c  = i % CDIM;
    unsigned bt = i / CDIM + rows0;
    unsigned t  = bt & (TT - 1);
    int id = idx[bt];
    x[i] = load_in(tok, (size_t)id * CDIM + c, m) + load_in(pos, (size_t)t * CDIM + c, m);
}

// ------------------------------- layernorm ---------------------------------
// one wave per row (C=384 = 64 lanes * 6); x fp32 in, bf16 out; g/b bf16 (pbuf)
__global__ __launch_bounds__(256) void ln_kernel(const float* __restrict__ x,
                                                 const u16* __restrict__ g,
                                                 const u16* __restrict__ b,
                                                 u16* __restrict__ out) {
    const unsigned row  = blockIdx.x * 4 + (threadIdx.x >> 6);
    const unsigned lane = threadIdx.x & 63;
    const float* xr = x + (size_t)row * CDIM;
    float v[6]; float s = 0.f, s2 = 0.f;
#pragma unroll
    for (int j = 0; j < 6; j++) { v[j] = xr[lane + j * 64]; s += v[j]; s2 += v[j] * v[j]; }
#pragma unroll
    for (int off = 32; off; off >>= 1) { s += __shfl_xor(s, off); s2 += __shfl_xor(s2, off); }
    float mean = s * (1.f / CDIM);
    float var  = fmaxf(s2 * (1.f / CDIM) - mean * mean, 0.f);
    float rstd = rsqrtf(var + 1e-5f);
    u16* orow = out + (size_t)row * CDIM;
#pragma unroll
    for (int j = 0; j < 6; j++) {
        unsigned c = lane + j * 64;
        orow[c] = f2b((v[j] - mean) * rstd * b2f(g[c]) + b2f(b[c]));
    }
}

// --------------------------------- GEMM ------------------------------------
// C[M,N] = A[M,K] @ B[K,N], B given transposed (Bt[N,K]). bf16 in, fp32 acc.
// BIAS adds bias[N] (bf16); RELU; RESID: Cf = resid + acc (fp32, may alias
// resid); FOUT: Cf = acc (fp32, no resid); else Cb = bf16.
// NBOUND: N not multiple of 128 (LM head, N=80).
template<bool BIAS, bool RELU, bool RESID, bool NBOUND, bool FOUT>
__global__ __launch_bounds__(256)
void gemm_kernel(const u16* __restrict__ A, const u16* __restrict__ Bt,
                 const u16* __restrict__ bias, const float* resid,
                 u16* __restrict__ Cb, float* Cf,
                 int N, int K) {
    __shared__ __align__(16) u16 As[128 * 32];
    __shared__ __align__(16) u16 Bs[128 * 32];
    const int tid  = threadIdx.x;
    const int lane = tid & 63;
    const int wave = tid >> 6;
    const int quad = lane >> 4;
    const int l16  = lane & 15;
    const int wm = wave >> 1, wn = wave & 1;

    const long m0 = (long)blockIdx.y * 128;
    const long n0 = (long)blockIdx.x * 128;

    const int ar = tid >> 1;          // tile row handled by this thread (0..127)
    const int ac = (tid & 1) * 16;    // col chunk (0 or 16)

    const u16* Ag = A + (m0 + ar) * K + ac;
    bool bok = true;
    long brow = n0 + ar;
    if (NBOUND) bok = (brow < N);
    const u16* Bg = Bt + (bok ? brow : 0) * K + ac;

    f32x4 acc[4][4];
#pragma unroll
    for (int i = 0; i < 4; i++)
#pragma unroll
        for (int j = 0; j < 4; j++) acc[i][j] = f32x4{0.f, 0.f, 0.f, 0.f};

    for (int k0 = 0; k0 < K; k0 += 32) {
        uint4 av0 = *(const uint4*)(Ag);
        uint4 av1 = *(const uint4*)(Ag + 8);
        uint4 bv0, bv1;
        if (!NBOUND || bok) { bv0 = *(const uint4*)(Bg); bv1 = *(const uint4*)(Bg + 8); }
        else                { bv0 = make_uint4(0, 0, 0, 0); bv1 = bv0; }
        __syncthreads();   // previous iteration's LDS reads complete
        *(uint4*)(&As[ar * 32 + ac])     = av0;
        *(uint4*)(&As[ar * 32 + ac + 8]) = av1;
        *(uint4*)(&Bs[ar * 32 + ac])     = bv0;
        *(uint4*)(&Bs[ar * 32 + ac + 8]) = bv1;
        __syncthreads();
        bf16x8 af[4], bfr[4];
#pragma unroll
        for (int i = 0; i < 4; i++)
            af[i] = *(const bf16x8*)(&As[(wm * 64 + i * 16 + l16) * 32 + quad * 8]);
#pragma unroll
        for (int j = 0; j < 4; j++)
            bfr[j] = *(const bf16x8*)(&Bs[(wn * 64 + j * 16 + l16) * 32 + quad * 8]);
#pragma unroll
        for (int i = 0; i < 4; i++)
#pragma unroll
            for (int j = 0; j < 4; j++)
                acc[i][j] = __builtin_amdgcn_mfma_f32_16x16x32_bf16(af[i], bfr[j], acc[i][j], 0, 0, 0);
        Ag += 32; Bg += 32;
    }

    // epilogue: C/D layout col = lane&15, row = quad*4 + reg
#pragma unroll
    for (int j = 0; j < 4; j++) {
        const int col = (int)n0 + wn * 64 + j * 16 + l16;
        float bv = 0.f;
        if (BIAS) bv = (!NBOUND || col < N) ? b2f(bias[col]) : 0.f;
#pragma unroll
        for (int i = 0; i < 4; i++) {
#pragma unroll
            for (int r = 0; r < 4; r++) {
                const long row = m0 + wm * 64 + i * 16 + quad * 4 + r;
                float v = acc[i][j][r] + bv;
                if (RELU) v = fmaxf(v, 0.f);
                if (RESID) {
                    Cf[row * N + col] = resid[row * N + col] + v;
                } else if (FOUT) {
                    if (!NBOUND || col < N) Cf[row * N + col] = v;
                } else {
                    if (!NBOUND || col < N) Cb[row * N + col] = f2b(v);
                }
            }
        }
    }
}

// ------------------------------- attention ---------------------------------
// wave = one (seq, head); lane = t*2 + half; each thread owns 32 of DH=64.
// Causal T=32; scores masked to -1e30 (exp -> exactly 0) => uniform flow,
// wave-uniform K/V row loads. ~90 live VGPRs, no spill.
// qkv: [rows][1152] bf16 (q | k | v, head-major within each 384 chunk)
__global__ __launch_bounds__(256, 4) void attn_kernel(const u16* __restrict__ qkv,
                                                      u16* __restrict__ o) {
    const int gw   = blockIdx.x * 4 + (threadIdx.x >> 6);   // global wave id
    const int seq  = gw / HH;
    const int h    = gw - seq * HH;
    const int lane = threadIdx.x & 63;
    const int t    = lane >> 1;
    const int half = lane & 1;
    const u16* base = qkv + (size_t)seq * TT * QKVN;
    const int hoff  = h * DHEAD + half * 32;

    float q[32];
    {
        const uint4* qp = (const uint4*)(base + t * QKVN + hoff);
#pragma unroll
        for (int i = 0; i < 4; i++) unpack8(qp[i], q + i * 8);
    }

    float sc[TT];
    float mx = -1e30f;
#pragma unroll
    for (int s = 0; s < TT; s++) {
        const uint4* kp = (const uint4*)(base + s * QKVN + 384 + hoff);
        float part = 0.f;
#pragma unroll
        for (int i = 0; i < 4; i++) {
            float kf[8]; unpack8(kp[i], kf);
#pragma unroll
            for (int d = 0; d < 8; d++) part += q[i * 8 + d] * kf[d];
        }
        float full = part + __shfl_xor(part, 1);
        float val = (s <= t) ? full * 0.125f : -1e30f;   // DH^-0.5
        sc[s] = val;
        mx = fmaxf(mx, val);
    }
    float sum = 0.f;
#pragma unroll
    for (int s = 0; s < TT; s++) { sc[s] = __expf(sc[s] - mx); sum += sc[s]; }
    const float inv = 1.f / sum;

    float oacc[32];
#pragma unroll
    for (int d = 0; d < 32; d++) oacc[d] = 0.f;
#pragma unroll
    for (int s = 0; s < TT; s++) {
        const float p = sc[s] * inv;                      // 0 for masked s
        const uint4* vp = (const uint4*)(base + s * QKVN + 768 + hoff);
#pragma unroll
        for (int i = 0; i < 4; i++) {
            float vf[8]; unpack8(vp[i], vf);
#pragma unroll
            for (int d = 0; d < 8; d++) oacc[i * 8 + d] += p * vf[d];
        }
    }

    u16* orow = o + ((size_t)seq * TT + t) * CDIM + hoff;
    uint4 st[4];
    unsigned* sw = (unsigned*)st;
#pragma unroll
    for (int j = 0; j < 16; j++)
        sw[j] = (unsigned)f2b(oacc[2 * j]) | ((unsigned)f2b(oacc[2 * j + 1]) << 16);
#pragma unroll
    for (int i = 0; i < 4; i++) ((uint4*)orow)[i] = st[i];
}

// ------------------------------- launcher ----------------------------------
extern "C" void kernel_launch(void* const* d_in, const int* in_sizes, int n_in,
                              void* d_out, int out_size, void* d_ws, size_t ws_size,
                              hipStream_t stream) {
    const int*  idx  = (const int*)d_in[0];
    const void* tok  = d_in[1];
    const void* pos  = d_in[2];
    const void* ln1g = d_in[3];
    const void* ln1b = d_in[4];
    const void* Wq   = d_in[5];
    const void* Wk   = d_in[6];
    const void* Wv   = d_in[7];
    const void* Wo   = d_in[8];
    const void* bo   = d_in[9];
    const void* ln2g = d_in[10];
    const void* ln2b = d_in[11];
    const void* W1   = d_in[12];
    const void* b1   = d_in[13];
    const void* W2   = d_in[14];
    const void* b2   = d_in[15];
    const void* lnfg = d_in[16];
    const void* lnfb = d_in[17];
    const void* Wlm  = d_in[18];
    const void* blm  = d_in[19];

    // ---- workspace layout (adaptive batch chunking) ----
    const size_t wq_b  = (size_t)LLAY * QKVN * CDIM * 2;
    const size_t wo_b  = (size_t)LLAY * CDIM * CDIM * 2;
    const size_t w1_b  = (size_t)LLAY * FFDIM * CDIM * 2;
    const size_t w2_b  = (size_t)LLAY * CDIM * FFDIM * 2;
    const size_t wlm_b = (size_t)VOCAB * CDIM * 2;
    const size_t wts   = wq_b + wo_b + w1_b + w2_b + wlm_b;   // ~21.3 MB

    // pbuf: converted 1-D params, bf16 elements
    const unsigned P_LN1G = 0,      P_LN1B = 2304,  P_BO  = 4608;
    const unsigned P_LN2G = 6912,   P_LN2B = 9216,  P_B1  = 11520;
    const unsigned P_B2   = 20736,  P_LNFG = 23040, P_LNFB = 23424;
    const unsigned P_BLM  = 23808,  P_TOT  = 23888;
    const size_t pbuf_b = ((size_t)P_TOT * 2 + 255) & ~(size_t)255;

    // per-row bytes: x fp32 1536 + h bf16 768 + S (max(qkv+o, u)) 3072 = 5376
    int NC = 32;
    {
        const int cand[6] = {1, 2, 4, 8, 16, 32};
        for (int ci = 0; ci < 6; ci++) {
            size_t rows_c = (size_t)M_TOK / cand[ci];
            size_t need = rows_c * 5376 + wts + pbuf_b + 4096;
            if (need <= ws_size) { NC = cand[ci]; break; }
        }
    }
    const size_t rows = (size_t)M_TOK / NC;

    char* ws = (char*)d_ws;
    size_t off = 0;
    float* x    = (float*)(ws + off); off += rows * CDIM * 4;         // fp32 residual
    u16*   h    = (u16*)(ws + off);   off += rows * CDIM * 2;         // LN out
    char*  S    = ws + off;           off += rows * 3072;             // shared scratch
    u16*   qkv  = (u16*)S;                                            // rows*1152 bf16
    u16*   o    = (u16*)(S + rows * QKVN * 2);                        // rows*384 bf16
    u16*   u    = (u16*)S;                                            // rows*1536 bf16 (qkv,o dead)
    u16* wqkvT  = (u16*)(ws + off);   off += wq_b;
    u16* woT    = (u16*)(ws + off);   off += wo_b;
    u16* w1T    = (u16*)(ws + off);   off += w1_b;
    u16* w2T    = (u16*)(ws + off);   off += w2_b;
    u16* wlmT   = (u16*)(ws + off);   off += wlm_b;
    u16* pbuf   = (u16*)(ws + off);   off += pbuf_b;
    int* flag   = (int*)(ws + off);   off += 256;

    // ---- dtype detect + param convert + weight repack (once per call) ----
    detect_dtype_kernel<<<1, 64, 0, stream>>>(ln1g, flag);

    struct { const void* src; unsigned doff, n; } cv[10] = {
        { ln1g, P_LN1G, 2304 }, { ln1b, P_LN1B, 2304 }, { bo, P_BO, 2304 },
        { ln2g, P_LN2G, 2304 }, { ln2b, P_LN2B, 2304 }, { b1, P_B1, 9216 },
        { b2,   P_B2,   2304 }, { lnfg, P_LNFG, 384 },  { lnfb, P_LNFB, 384 },
        { blm,  P_BLM,  80 },
    };
    for (int i = 0; i < 10; i++)
        cvt_kernel<<<(cv[i].n + 255) / 256, 256, 0, stream>>>(cv[i].src, pbuf + cv[i].doff, cv[i].n, flag);

    {
        unsigned tq = (unsigned)LLAY * QKVN * CDIM;
        pack_qkv_kernel<<<(tq + 255) / 256, 256, 0, stream>>>(Wq, Wk, Wv, wqkvT, flag);
        unsigned t1 = (unsigned)LLAY * CDIM * CDIM;
        transpose_kernel<<<(t1 + 255) / 256, 256, 0, stream>>>(Wo, woT, CDIM, CDIM, t1, flag);
        unsigned t2t = (unsigned)LLAY * CDIM * FFDIM;
        transpose_kernel<<<(t2t + 255) / 256, 256, 0, stream>>>(W1, w1T, CDIM, FFDIM, t2t, flag);
        transpose_kernel<<<(t2t + 255) / 256, 256, 0, stream>>>(W2, w2T, FFDIM, CDIM, t2t, flag);
        unsigned t3 = (unsigned)VOCAB * CDIM;
        transpose_kernel<<<(t3 + 255) / 256, 256, 0, stream>>>(Wlm, wlmT, CDIM, VOCAB, t3, flag);
    }

    // ---- batch-chunked forward ----
    for (int c = 0; c < NC; c++) {
        const size_t r0 = c * rows;            // first token-row of chunk
        embed_kernel<<<(rows * CDIM) / 256, 256, 0, stream>>>(idx, tok, pos, x, (unsigned)r0, flag);

        for (int l = 0; l < LLAY; l++) {
            ln_kernel<<<rows / 4, 256, 0, stream>>>(x, pbuf + P_LN1G + l * CDIM, pbuf + P_LN1B + l * CDIM, h);
            gemm_kernel<false, false, false, false, false><<<dim3(QKVN / 128, rows / 128), 256, 0, stream>>>(
                h, wqkvT + (size_t)l * QKVN * CDIM, nullptr, nullptr, qkv, nullptr, QKVN, CDIM);
            attn_kernel<<<(rows / TT) * HH / 4, 256, 0, stream>>>(qkv, o);
            gemm_kernel<true, false, true, false, false><<<dim3(CDIM / 128, rows / 128), 256, 0, stream>>>(
                o, woT + (size_t)l * CDIM * CDIM, pbuf + P_BO + l * CDIM, x, nullptr, x, CDIM, CDIM);
            ln_kernel<<<rows / 4, 256, 0, stream>>>(x, pbuf + P_LN2G + l * CDIM, pbuf + P_LN2B + l * CDIM, h);
            gemm_kernel<true, true, false, false, false><<<dim3(FFDIM / 128, rows / 128), 256, 0, stream>>>(
                h, w1T + (size_t)l * FFDIM * CDIM, pbuf + P_B1 + l * FFDIM, nullptr, u, nullptr, FFDIM, CDIM);
            gemm_kernel<true, false, true, false, false><<<dim3(CDIM / 128, rows / 128), 256, 0, stream>>>(
                u, w2T + (size_t)l * CDIM * FFDIM, pbuf + P_B2 + l * CDIM, x, nullptr, x, CDIM, FFDIM);
        }

        ln_kernel<<<rows / 4, 256, 0, stream>>>(x, pbuf + P_LNFG, pbuf + P_LNFB, h);
        gemm_kernel<true, false, false, true, true><<<dim3(1, rows / 128), 256, 0, stream>>>(
            h, wlmT, pbuf + P_BLM, nullptr, nullptr, (float*)d_out + r0 * VOCAB, VOCAB, CDIM);
    }
}

// Round 6
// 10079.224 us; speedup vs baseline: 1.3186x; 1.3186x over previous
//
#include <hip/hip_runtime.h>
#include <hip/hip_fp16.h>
#include <stdint.h>

// ---------------------------------------------------------------------------
// GPT forward, MI355X. Round 6: kill the attention spill.
//  - Round 5 post-mortem: attn FETCH 164 MB (unique 37.7), WRITE 309 MB
//    (true 12.6), VGPR=64 -> the allocator spilled q/sc/oacc to scratch
//    again. 2.4 TB/s of pure spill traffic = the 200 us.
//  - Fix: (1) online softmax -- no sc[32] array spanning the s-loop; q/oacc
//    only indexed by constant-bound inner loops (SROA-safe). Live state ~85
//    floats. (2) __launch_bounds__(256,2) -> VGPR cap 256, no excuse to
//    spill. Masked steps: s=0 always unmasked so m finite; masked p=0 exact.
// GEMMs / LN / embed unchanged (working, absmax 0.0156).
// ---------------------------------------------------------------------------

typedef unsigned short u16;
typedef __bf16 bf16x8 __attribute__((ext_vector_type(8)));
typedef float f32x4 __attribute__((ext_vector_type(4)));

#define M_TOK 131072   // B*T
#define CDIM  384
#define TT    32
#define HH    6
#define DHEAD 64
#define LLAY  6
#define VOCAB 80
#define FFDIM 1536
#define QKVN  1152

__device__ __forceinline__ float b2f(u16 v) {
    union { unsigned int u; float f; } x; x.u = ((unsigned int)v) << 16; return x.f;
}
__device__ __forceinline__ u16 f2b(float f) {
    union { float f; unsigned int u; } x; x.f = f;
    unsigned int r = (x.u + 0x7fffu + ((x.u >> 16) & 1u)) >> 16;   // RNE
    return (u16)r;
}
// unpack 8 bf16 (uint4) -> 8 fp32; 1 VALU op per element
__device__ __forceinline__ void unpack8(uint4 v, float* f) {
    const unsigned w[4] = {v.x, v.y, v.z, v.w};
#pragma unroll
    for (int j = 0; j < 4; j++) {
        union { unsigned u; float f; } a, b;
        a.u = w[j] << 16;
        b.u = w[j] & 0xffff0000u;
        f[2 * j]     = a.f;
        f[2 * j + 1] = b.f;
    }
}
// mode: 0 = fp32, 1 = bf16, 2 = fp16
__device__ __forceinline__ float load_in(const void* p, size_t i, int m) {
    if (m == 0) return ((const float*)p)[i];
    u16 v = ((const u16*)p)[i];
    if (m == 1) return b2f(v);
    __half h; *(u16*)&h = v; return __half2float(h);
}

// --------------------------- dtype detection -------------------------------
__global__ void detect_dtype_kernel(const void* ln1g, int* flag) {
    if (threadIdx.x == 0 && blockIdx.x == 0) {
        unsigned w = *(const unsigned*)ln1g;       // ln1_g is all 1.0
        int m = 0;
        if (w == 0x3F803F80u) m = 1;               // bf16 ones
        else if (w == 0x3C003C00u) m = 2;          // fp16 ones
        *flag = m;
    }
}

// --------------------------- param convert ---------------------------------
__global__ void cvt_kernel(const void* __restrict__ src, u16* __restrict__ dst,
                           unsigned n, const int* __restrict__ flag) {
    const int m = *flag;
    unsigned i = blockIdx.x * 256 + threadIdx.x;
    if (i < n) dst[i] = f2b(load_in(src, i, m));
}

// --------------------------- weight repack ---------------------------------
// dst [L][Cc][R] = src [L][R][Cc] transposed per layer (B^T layout for GEMM)
__global__ void transpose_kernel(const void* __restrict__ src, u16* __restrict__ dst,
                                 int R, int Cc, unsigned total,
                                 const int* __restrict__ flag) {
    const int m = *flag;
    unsigned i = blockIdx.x * 256 + threadIdx.x;
    if (i >= total) return;
    unsigned c  = i % R;
    unsigned t2 = i / R;
    unsigned n  = t2 % Cc;
    unsigned l  = t2 / Cc;
    dst[i] = f2b(load_in(src, ((size_t)l * R + c) * Cc + n, m));
}

// dst[l][n][c] (n in [0,1152)): n<384 -> Wq[l][n>>6][c][n&63]; then Wk; then Wv
__global__ void pack_qkv_kernel(const void* __restrict__ Wq, const void* __restrict__ Wk,
                                const void* __restrict__ Wv, u16* __restrict__ dst,
                                const int* __restrict__ flag) {
    const int m = *flag;
    unsigned i = blockIdx.x * 256 + threadIdx.x;
    const unsigned total = (unsigned)LLAY * QKVN * CDIM;
    if (i >= total) return;
    unsigned c  = i % CDIM;
    unsigned t2 = i / CDIM;
    unsigned n  = t2 % QKVN;
    unsigned l  = t2 / QKVN;
    const void* W = (n < 384) ? Wq : (n < 768) ? Wk : Wv;
    unsigned nn = n % 384;
    unsigned hh = nn >> 6, d = nn & 63;
    dst[i] = f2b(load_in(W, (((size_t)l * HH + hh) * CDIM + c) * DHEAD + d, m));
}

// ------------------------------- embedding ---------------------------------
__global__ void embed_kernel(const int* __restrict__ idx, const void* __restrict__ tok,
                             const void* __restrict__ pos, float* __restrict__ x,
                             unsigned rows0, const int* __restrict__ flag) {
    const int m = *flag;
    unsigned i = blockIdx.x * 256 + threadIdx.x;
    unsigned c  = i % CDIM;
    unsigned bt = i / CDIM + rows0;
    unsigned t  = bt & (TT - 1);
    int id = idx[bt];
    x[i] = load_in(tok, (size_t)id * CDIM + c, m) + load_in(pos, (size_t)t * CDIM + c, m);
}

// ------------------------------- layernorm ---------------------------------
// one wave per row (C=384 = 64 lanes * 6); x fp32 in, bf16 out; g/b bf16 (pbuf)
__global__ __launch_bounds__(256) void ln_kernel(const float* __restrict__ x,
                                                 const u16* __restrict__ g,
                                                 const u16* __restrict__ b,
                                                 u16* __restrict__ out) {
    const unsigned row  = blockIdx.x * 4 + (threadIdx.x >> 6);
    const unsigned lane = threadIdx.x & 63;
    const float* xr = x + (size_t)row * CDIM;
    float v[6]; float s = 0.f, s2 = 0.f;
#pragma unroll
    for (int j = 0; j < 6; j++) { v[j] = xr[lane + j * 64]; s += v[j]; s2 += v[j] * v[j]; }
#pragma unroll
    for (int off = 32; off; off >>= 1) { s += __shfl_xor(s, off); s2 += __shfl_xor(s2, off); }
    float mean = s * (1.f / CDIM);
    float var  = fmaxf(s2 * (1.f / CDIM) - mean * mean, 0.f);
    float rstd = rsqrtf(var + 1e-5f);
    u16* orow = out + (size_t)row * CDIM;
#pragma unroll
    for (int j = 0; j < 6; j++) {
        unsigned c = lane + j * 64;
        orow[c] = f2b((v[j] - mean) * rstd * b2f(g[c]) + b2f(b[c]));
    }
}

// --------------------------------- GEMM ------------------------------------
// C[M,N] = A[M,K] @ B[K,N], B given transposed (Bt[N,K]). bf16 in, fp32 acc.
// BIAS adds bias[N] (bf16); RELU; RESID: Cf = resid + acc (fp32, may alias
// resid); FOUT: Cf = acc (fp32, no resid); else Cb = bf16.
// NBOUND: N not multiple of 128 (LM head, N=80).
template<bool BIAS, bool RELU, bool RESID, bool NBOUND, bool FOUT>
__global__ __launch_bounds__(256)
void gemm_kernel(const u16* __restrict__ A, const u16* __restrict__ Bt,
                 const u16* __restrict__ bias, const float* resid,
                 u16* __restrict__ Cb, float* Cf,
                 int N, int K) {
    __shared__ __align__(16) u16 As[128 * 32];
    __shared__ __align__(16) u16 Bs[128 * 32];
    const int tid  = threadIdx.x;
    const int lane = tid & 63;
    const int wave = tid >> 6;
    const int quad = lane >> 4;
    const int l16  = lane & 15;
    const int wm = wave >> 1, wn = wave & 1;

    const long m0 = (long)blockIdx.y * 128;
    const long n0 = (long)blockIdx.x * 128;

    const int ar = tid >> 1;          // tile row handled by this thread (0..127)
    const int ac = (tid & 1) * 16;    // col chunk (0 or 16)

    const u16* Ag = A + (m0 + ar) * K + ac;
    bool bok = true;
    long brow = n0 + ar;
    if (NBOUND) bok = (brow < N);
    const u16* Bg = Bt + (bok ? brow : 0) * K + ac;

    f32x4 acc[4][4];
#pragma unroll
    for (int i = 0; i < 4; i++)
#pragma unroll
        for (int j = 0; j < 4; j++) acc[i][j] = f32x4{0.f, 0.f, 0.f, 0.f};

    for (int k0 = 0; k0 < K; k0 += 32) {
        uint4 av0 = *(const uint4*)(Ag);
        uint4 av1 = *(const uint4*)(Ag + 8);
        uint4 bv0, bv1;
        if (!NBOUND || bok) { bv0 = *(const uint4*)(Bg); bv1 = *(const uint4*)(Bg + 8); }
        else                { bv0 = make_uint4(0, 0, 0, 0); bv1 = bv0; }
        __syncthreads();   // previous iteration's LDS reads complete
        *(uint4*)(&As[ar * 32 + ac])     = av0;
        *(uint4*)(&As[ar * 32 + ac + 8]) = av1;
        *(uint4*)(&Bs[ar * 32 + ac])     = bv0;
        *(uint4*)(&Bs[ar * 32 + ac + 8]) = bv1;
        __syncthreads();
        bf16x8 af[4], bfr[4];
#pragma unroll
        for (int i = 0; i < 4; i++)
            af[i] = *(const bf16x8*)(&As[(wm * 64 + i * 16 + l16) * 32 + quad * 8]);
#pragma unroll
        for (int j = 0; j < 4; j++)
            bfr[j] = *(const bf16x8*)(&Bs[(wn * 64 + j * 16 + l16) * 32 + quad * 8]);
#pragma unroll
        for (int i = 0; i < 4; i++)
#pragma unroll
            for (int j = 0; j < 4; j++)
                acc[i][j] = __builtin_amdgcn_mfma_f32_16x16x32_bf16(af[i], bfr[j], acc[i][j], 0, 0, 0);
        Ag += 32; Bg += 32;
    }

    // epilogue: C/D layout col = lane&15, row = quad*4 + reg
#pragma unroll
    for (int j = 0; j < 4; j++) {
        const int col = (int)n0 + wn * 64 + j * 16 + l16;
        float bv = 0.f;
        if (BIAS) bv = (!NBOUND || col < N) ? b2f(bias[col]) : 0.f;
#pragma unroll
        for (int i = 0; i < 4; i++) {
#pragma unroll
            for (int r = 0; r < 4; r++) {
                const long row = m0 + wm * 64 + i * 16 + quad * 4 + r;
                float v = acc[i][j][r] + bv;
                if (RELU) v = fmaxf(v, 0.f);
                if (RESID) {
                    Cf[row * N + col] = resid[row * N + col] + v;
                } else if (FOUT) {
                    if (!NBOUND || col < N) Cf[row * N + col] = v;
                } else {
                    if (!NBOUND || col < N) Cb[row * N + col] = f2b(v);
                }
            }
        }
    }
}

// ------------------------------- attention ---------------------------------
// wave = one (seq, head); lane = t*2 + half; thread owns 32 of DH=64.
// ONLINE softmax (running m, l; rescale oacc) -> no score array spans the
// s-loop; q/oacc only indexed by constant-bound inner loops (SROA-safe).
// s=0 is unmasked for every t so m is finite after step 0; masked steps
// give p = exp(-1e30 - m) = 0 exactly.
__global__ __launch_bounds__(256, 2) void attn_kernel(const u16* __restrict__ qkv,
                                                      u16* __restrict__ o) {
    const int gw   = blockIdx.x * 4 + (threadIdx.x >> 6);   // global wave id
    const int seq  = gw / HH;
    const int h    = gw - seq * HH;
    const int lane = threadIdx.x & 63;
    const int t    = lane >> 1;
    const int half = lane & 1;
    const u16* base = qkv + (size_t)seq * TT * QKVN;
    const int hoff  = h * DHEAD + half * 32;

    float q[32];
    {
        const uint4* qp = (const uint4*)(base + t * QKVN + hoff);
#pragma unroll
        for (int i = 0; i < 4; i++) unpack8(qp[i], q + i * 8);
    }

    float m = -1e30f, l = 0.f;
    float oacc[32];
#pragma unroll
    for (int d = 0; d < 32; d++) oacc[d] = 0.f;

    for (int s = 0; s < TT; s++) {
        const uint4* kp = (const uint4*)(base + s * QKVN + 384 + hoff);
        const uint4* vp = (const uint4*)(base + s * QKVN + 768 + hoff);
        float part = 0.f;
#pragma unroll
        for (int i = 0; i < 4; i++) {
            float kf[8]; unpack8(kp[i], kf);
#pragma unroll
            for (int d = 0; d < 8; d++) part += q[i * 8 + d] * kf[d];
        }
        const float full = part + __shfl_xor(part, 1);
        const float scv  = (s <= t) ? full * 0.125f : -1e30f;   // DH^-0.5
        const float newm  = fmaxf(m, scv);
        const float alpha = __expf(m - newm);       // 0 on first step
        const float p     = __expf(scv - newm);     // 0 for masked s
#pragma unroll
        for (int i = 0; i < 4; i++) {
            float vf[8]; unpack8(vp[i], vf);
#pragma unroll
            for (int d = 0; d < 8; d++)
                oacc[i * 8 + d] = oacc[i * 8 + d] * alpha + p * vf[d];
        }
        l = l * alpha + p;
        m = newm;
    }
    const float inv = 1.f / l;

    u16* orow = o + ((size_t)seq * TT + t) * CDIM + hoff;
    uint4 st[4];
    unsigned* sw = (unsigned*)st;
#pragma unroll
    for (int j = 0; j < 16; j++)
        sw[j] = (unsigned)f2b(oacc[2 * j] * inv) | ((unsigned)f2b(oacc[2 * j + 1] * inv) << 16);
#pragma unroll
    for (int i = 0; i < 4; i++) ((uint4*)orow)[i] = st[i];
}

// ------------------------------- launcher ----------------------------------
extern "C" void kernel_launch(void* const* d_in, const int* in_sizes, int n_in,
                              void* d_out, int out_size, void* d_ws, size_t ws_size,
                              hipStream_t stream) {
    const int*  idx  = (const int*)d_in[0];
    const void* tok  = d_in[1];
    const void* pos  = d_in[2];
    const void* ln1g = d_in[3];
    const void* ln1b = d_in[4];
    const void* Wq   = d_in[5];
    const void* Wk   = d_in[6];
    const void* Wv   = d_in[7];
    const void* Wo   = d_in[8];
    const void* bo   = d_in[9];
    const void* ln2g = d_in[10];
    const void* ln2b = d_in[11];
    const void* W1   = d_in[12];
    const void* b1   = d_in[13];
    const void* W2   = d_in[14];
    const void* b2   = d_in[15];
    const void* lnfg = d_in[16];
    const void* lnfb = d_in[17];
    const void* Wlm  = d_in[18];
    const void* blm  = d_in[19];

    // ---- workspace layout (adaptive batch chunking) ----
    const size_t wq_b  = (size_t)LLAY * QKVN * CDIM * 2;
    const size_t wo_b  = (size_t)LLAY * CDIM * CDIM * 2;
    const size_t w1_b  = (size_t)LLAY * FFDIM * CDIM * 2;
    const size_t w2_b  = (size_t)LLAY * CDIM * FFDIM * 2;
    const size_t wlm_b = (size_t)VOCAB * CDIM * 2;
    const size_t wts   = wq_b + wo_b + w1_b + w2_b + wlm_b;   // ~21.3 MB

    // pbuf: converted 1-D params, bf16 elements
    const unsigned P_LN1G = 0,      P_LN1B = 2304,  P_BO  = 4608;
    const unsigned P_LN2G = 6912,   P_LN2B = 9216,  P_B1  = 11520;
    const unsigned P_B2   = 20736,  P_LNFG = 23040, P_LNFB = 23424;
    const unsigned P_BLM  = 23808,  P_TOT  = 23888;
    const size_t pbuf_b = ((size_t)P_TOT * 2 + 255) & ~(size_t)255;

    // per-row bytes: x fp32 1536 + h bf16 768 + S (max(qkv+o, u)) 3072 = 5376
    int NC = 32;
    {
        const int cand[6] = {1, 2, 4, 8, 16, 32};
        for (int ci = 0; ci < 6; ci++) {
            size_t rows_c = (size_t)M_TOK / cand[ci];
            size_t need = rows_c * 5376 + wts + pbuf_b + 4096;
            if (need <= ws_size) { NC = cand[ci]; break; }
        }
    }
    const size_t rows = (size_t)M_TOK / NC;

    char* ws = (char*)d_ws;
    size_t off = 0;
    float* x    = (float*)(ws + off); off += rows * CDIM * 4;         // fp32 residual
    u16*   h    = (u16*)(ws + off);   off += rows * CDIM * 2;         // LN out
    char*  S    = ws + off;           off += rows * 3072;             // shared scratch
    u16*   qkv  = (u16*)S;                                            // rows*1152 bf16
    u16*   o    = (u16*)(S + rows * QKVN * 2);                        // rows*384 bf16
    u16*   u    = (u16*)S;                                            // rows*1536 bf16 (qkv,o dead)
    u16* wqkvT  = (u16*)(ws + off);   off += wq_b;
    u16* woT    = (u16*)(ws + off);   off += wo_b;
    u16* w1T    = (u16*)(ws + off);   off += w1_b;
    u16* w2T    = (u16*)(ws + off);   off += w2_b;
    u16* wlmT   = (u16*)(ws + off);   off += wlm_b;
    u16* pbuf   = (u16*)(ws + off);   off += pbuf_b;
    int* flag   = (int*)(ws + off);   off += 256;

    // ---- dtype detect + param convert + weight repack (once per call) ----
    detect_dtype_kernel<<<1, 64, 0, stream>>>(ln1g, flag);

    struct { const void* src; unsigned doff, n; } cv[10] = {
        { ln1g, P_LN1G, 2304 }, { ln1b, P_LN1B, 2304 }, { bo, P_BO, 2304 },
        { ln2g, P_LN2G, 2304 }, { ln2b, P_LN2B, 2304 }, { b1, P_B1, 9216 },
        { b2,   P_B2,   2304 }, { lnfg, P_LNFG, 384 },  { lnfb, P_LNFB, 384 },
        { blm,  P_BLM,  80 },
    };
    for (int i = 0; i < 10; i++)
        cvt_kernel<<<(cv[i].n + 255) / 256, 256, 0, stream>>>(cv[i].src, pbuf + cv[i].doff, cv[i].n, flag);

    {
        unsigned tq = (unsigned)LLAY * QKVN * CDIM;
        pack_qkv_kernel<<<(tq + 255) / 256, 256, 0, stream>>>(Wq, Wk, Wv, wqkvT, flag);
        unsigned t1 = (unsigned)LLAY * CDIM * CDIM;
        transpose_kernel<<<(t1 + 255) / 256, 256, 0, stream>>>(Wo, woT, CDIM, CDIM, t1, flag);
        unsigned t2t = (unsigned)LLAY * CDIM * FFDIM;
        transpose_kernel<<<(t2t + 255) / 256, 256, 0, stream>>>(W1, w1T, CDIM, FFDIM, t2t, flag);
        transpose_kernel<<<(t2t + 255) / 256, 256, 0, stream>>>(W2, w2T, FFDIM, CDIM, t2t, flag);
        unsigned t3 = (unsigned)VOCAB * CDIM;
        transpose_kernel<<<(t3 + 255) / 256, 256, 0, stream>>>(Wlm, wlmT, CDIM, VOCAB, t3, flag);
    }

    // ---- batch-chunked forward ----
    for (int c = 0; c < NC; c++) {
        const size_t r0 = c * rows;            // first token-row of chunk
        embed_kernel<<<(rows * CDIM) / 256, 256, 0, stream>>>(idx, tok, pos, x, (unsigned)r0, flag);

        for (int l = 0; l < LLAY; l++) {
            ln_kernel<<<rows / 4, 256, 0, stream>>>(x, pbuf + P_LN1G + l * CDIM, pbuf + P_LN1B + l * CDIM, h);
            gemm_kernel<false, false, false, false, false><<<dim3(QKVN / 128, rows / 128), 256, 0, stream>>>(
                h, wqkvT + (size_t)l * QKVN * CDIM, nullptr, nullptr, qkv, nullptr, QKVN, CDIM);
            attn_kernel<<<(rows / TT) * HH / 4, 256, 0, stream>>>(qkv, o);
            gemm_kernel<true, false, true, false, false><<<dim3(CDIM / 128, rows / 128), 256, 0, stream>>>(
                o, woT + (size_t)l * CDIM * CDIM, pbuf + P_BO + l * CDIM, x, nullptr, x, CDIM, CDIM);
            ln_kernel<<<rows / 4, 256, 0, stream>>>(x, pbuf + P_LN2G + l * CDIM, pbuf + P_LN2B + l * CDIM, h);
            gemm_kernel<true, true, false, false, false><<<dim3(FFDIM / 128, rows / 128), 256, 0, stream>>>(
                h, w1T + (size_t)l * FFDIM * CDIM, pbuf + P_B1 + l * FFDIM, nullptr, u, nullptr, FFDIM, CDIM);
            gemm_kernel<true, false, true, false, false><<<dim3(CDIM / 128, rows / 128), 256, 0, stream>>>(
                u, w2T + (size_t)l * CDIM * FFDIM, pbuf + P_B2 + l * CDIM, x, nullptr, x, CDIM, FFDIM);
        }

        ln_kernel<<<rows / 4, 256, 0, stream>>>(x, pbuf + P_LNFG, pbuf + P_LNFB, h);
        gemm_kernel<true, false, false, true, true><<<dim3(1, rows / 128), 256, 0, stream>>>(
            h, wlmT, pbuf + P_BLM, nullptr, nullptr, (float*)d_out + r0 * VOCAB, VOCAB, CDIM);
    }
}

// Round 7
// 9018.656 us; speedup vs baseline: 1.4737x; 1.1176x over previous
//
#include <hip/hip_runtime.h>
#include <hip/hip_fp16.h>
#include <stdint.h>

// ---------------------------------------------------------------------------
// GPT forward, MI355X. Round 7: GEMM rewrite (m97 pattern).
//  - Round 6: attn fixed (gone from top-5); GEMMs now dominate. MLP1 GEMM
//    126 us: MfmaUtil 12%, 9.4M LDS-conflict cycles (fragment reads hit 4
//    bank-windows instead of 8), FETCH 184 MB vs 14 unique (n-fastest grid
//    order scatters same-m blocks across XCDs), register-staged LDS.
//  - Now: global_load_lds width=16 staging; XOR-swizzled LDS slots
//    (row,q)->row*64+(q^((row>>1)&3))*16 realized via per-lane global
//    addresses (wave-uniform lds base + lane*16 constraint respected);
//    XCD-grouped 1-D block swizzle (same-m n-tiles consecutive on one XCD).
// attn / LN / embed / repack unchanged.
// ---------------------------------------------------------------------------

typedef unsigned short u16;
typedef __bf16 bf16x8 __attribute__((ext_vector_type(8)));
typedef float f32x4 __attribute__((ext_vector_type(4)));

#define M_TOK 131072   // B*T
#define CDIM  384
#define TT    32
#define HH    6
#define DHEAD 64
#define LLAY  6
#define VOCAB 80
#define FFDIM 1536
#define QKVN  1152

__device__ __forceinline__ float b2f(u16 v) {
    union { unsigned int u; float f; } x; x.u = ((unsigned int)v) << 16; return x.f;
}
__device__ __forceinline__ u16 f2b(float f) {
    union { float f; unsigned int u; } x; x.f = f;
    unsigned int r = (x.u + 0x7fffu + ((x.u >> 16) & 1u)) >> 16;   // RNE
    return (u16)r;
}
// async global->LDS, 16B per lane; lds arg is the WAVE-uniform base
__device__ __forceinline__ void gload16(const u16* g, u16* l) {
    __builtin_amdgcn_global_load_lds(
        (const __attribute__((address_space(1))) void*)g,
        (__attribute__((address_space(3))) void*)l,
        16, 0, 0);
}
// unpack 8 bf16 (uint4) -> 8 fp32; 1 VALU op per element
__device__ __forceinline__ void unpack8(uint4 v, float* f) {
    const unsigned w[4] = {v.x, v.y, v.z, v.w};
#pragma unroll
    for (int j = 0; j < 4; j++) {
        union { unsigned u; float f; } a, b;
        a.u = w[j] << 16;
        b.u = w[j] & 0xffff0000u;
        f[2 * j]     = a.f;
        f[2 * j + 1] = b.f;
    }
}
// mode: 0 = fp32, 1 = bf16, 2 = fp16
__device__ __forceinline__ float load_in(const void* p, size_t i, int m) {
    if (m == 0) return ((const float*)p)[i];
    u16 v = ((const u16*)p)[i];
    if (m == 1) return b2f(v);
    __half h; *(u16*)&h = v; return __half2float(h);
}

// --------------------------- dtype detection -------------------------------
__global__ void detect_dtype_kernel(const void* ln1g, int* flag) {
    if (threadIdx.x == 0 && blockIdx.x == 0) {
        unsigned w = *(const unsigned*)ln1g;       // ln1_g is all 1.0
        int m = 0;
        if (w == 0x3F803F80u) m = 1;               // bf16 ones
        else if (w == 0x3C003C00u) m = 2;          // fp16 ones
        *flag = m;
    }
}

// --------------------------- param convert ---------------------------------
__global__ void cvt_kernel(const void* __restrict__ src, u16* __restrict__ dst,
                           unsigned n, const int* __restrict__ flag) {
    const int m = *flag;
    unsigned i = blockIdx.x * 256 + threadIdx.x;
    if (i < n) dst[i] = f2b(load_in(src, i, m));
}

// --------------------------- weight repack ---------------------------------
// dst [L][Cc][R] = src [L][R][Cc] transposed per layer (B^T layout for GEMM)
__global__ void transpose_kernel(const void* __restrict__ src, u16* __restrict__ dst,
                                 int R, int Cc, unsigned total,
                                 const int* __restrict__ flag) {
    const int m = *flag;
    unsigned i = blockIdx.x * 256 + threadIdx.x;
    if (i >= total) return;
    unsigned c  = i % R;
    unsigned t2 = i / R;
    unsigned n  = t2 % Cc;
    unsigned l  = t2 / Cc;
    dst[i] = f2b(load_in(src, ((size_t)l * R + c) * Cc + n, m));
}

// dst[l][n][c] (n in [0,1152)): n<384 -> Wq[l][n>>6][c][n&63]; then Wk; then Wv
__global__ void pack_qkv_kernel(const void* __restrict__ Wq, const void* __restrict__ Wk,
                                const void* __restrict__ Wv, u16* __restrict__ dst,
                                const int* __restrict__ flag) {
    const int m = *flag;
    unsigned i = blockIdx.x * 256 + threadIdx.x;
    const unsigned total = (unsigned)LLAY * QKVN * CDIM;
    if (i >= total) return;
    unsigned c  = i % CDIM;
    unsigned t2 = i / CDIM;
    unsigned n  = t2 % QKVN;
    unsigned l  = t2 / QKVN;
    const void* W = (n < 384) ? Wq : (n < 768) ? Wk : Wv;
    unsigned nn = n % 384;
    unsigned hh = nn >> 6, d = nn & 63;
    dst[i] = f2b(load_in(W, (((size_t)l * HH + hh) * CDIM + c) * DHEAD + d, m));
}

// ------------------------------- embedding ---------------------------------
__global__ void embed_kernel(const int* __restrict__ idx, const void* __restrict__ tok,
                             const void* __restrict__ pos, float* __restrict__ x,
                             unsigned rows0, const int* __restrict__ flag) {
    const int m = *flag;
    unsigned i = blockIdx.x * 256 + threadIdx.x;
    unsigned c  = i % CDIM;
    unsigned bt = i / CDIM + rows0;
    unsigned t  = bt & (TT - 1);
    int id = idx[bt];
    x[i] = load_in(tok, (size_t)id * CDIM + c, m) + load_in(pos, (size_t)t * CDIM + c, m);
}

// ------------------------------- layernorm ---------------------------------
// one wave per row (C=384 = 64 lanes * 6); x fp32 in, bf16 out; g/b bf16 (pbuf)
__global__ __launch_bounds__(256) void ln_kernel(const float* __restrict__ x,
                                                 const u16* __restrict__ g,
                                                 const u16* __restrict__ b,
                                                 u16* __restrict__ out) {
    const unsigned row  = blockIdx.x * 4 + (threadIdx.x >> 6);
    const unsigned lane = threadIdx.x & 63;
    const float* xr = x + (size_t)row * CDIM;
    float v[6]; float s = 0.f, s2 = 0.f;
#pragma unroll
    for (int j = 0; j < 6; j++) { v[j] = xr[lane + j * 64]; s += v[j]; s2 += v[j] * v[j]; }
#pragma unroll
    for (int off = 32; off; off >>= 1) { s += __shfl_xor(s, off); s2 += __shfl_xor(s2, off); }
    float mean = s * (1.f / CDIM);
    float var  = fmaxf(s2 * (1.f / CDIM) - mean * mean, 0.f);
    float rstd = rsqrtf(var + 1e-5f);
    u16* orow = out + (size_t)row * CDIM;
#pragma unroll
    for (int j = 0; j < 6; j++) {
        unsigned c = lane + j * 64;
        orow[c] = f2b((v[j] - mean) * rstd * b2f(g[c]) + b2f(b[c]));
    }
}

// --------------------------------- GEMM ------------------------------------
// C[M,N] = A[M,K] @ B[K,N], B given transposed (Bt[N,K]). bf16 in, fp32 acc.
// 128x128x32 tile, global_load_lds(16B) staging, XOR-swizzled LDS layout:
// 16B slot (row, q) stored at byte row*64 + (q^((row>>1)&3))*16 -> bank-
// conflict-free b128 fragment reads. 1-D grid with XCD-grouped swizzle.
// BIAS adds bias[N] (bf16); RELU; RESID: Cf = resid + acc (fp32, may alias
// resid); FOUT: Cf = acc; else Cb = bf16. NBOUND: N not multiple of 128.
template<bool BIAS, bool RELU, bool RESID, bool NBOUND, bool FOUT>
__global__ __launch_bounds__(256)
void gemm_kernel(const u16* __restrict__ A, const u16* __restrict__ Bt,
                 const u16* __restrict__ bias, const float* resid,
                 u16* __restrict__ Cb, float* Cf,
                 int N, int K, int nt) {
    __shared__ __align__(16) u16 As[128 * 32];
    __shared__ __align__(16) u16 Bs[128 * 32];
    const int tid  = threadIdx.x;
    const int lane = tid & 63;
    const int w    = tid >> 6;
    const int quad = lane >> 4;
    const int l16  = lane & 15;
    const int wm = w >> 1, wn = w & 1;

    // XCD-grouped block swizzle: consecutive ids round-robin XCDs; all
    // n-tiles of one m-tile land on one XCD back-to-back.
    const int id = blockIdx.x;
    const int s  = id >> 3;
    const int mtile = (id & 7) + 8 * (s / nt);
    const int ntile = s % nt;
    const long m0 = (long)mtile * 128;
    const long n0 = (long)ntile * 128;

    // staging: thread handles slots si (16B each), slot -> (row = si>>2,
    // qs = si&3); data chunk q = qs ^ ((row>>1)&3) of that row's 32-elem
    // K-slice. LDS dst = wave-uniform base + lane*16 (HW scatter).
    const int si0  = w * 128 + lane;
    const int si1  = si0 + 64;
    const int row0 = si0 >> 2, row1 = si1 >> 2;
    const int q0   = (si0 & 3) ^ ((row0 >> 1) & 3);
    const int q1   = (si1 & 3) ^ ((row1 >> 1) & 3);
    const u16* Ag0 = A + (m0 + row0) * K + q0 * 8;
    const u16* Ag1 = A + (m0 + row1) * K + q1 * 8;
    long br0 = n0 + row0, br1 = n0 + row1;
    if (NBOUND) { br0 = br0 < N ? br0 : N - 1; br1 = br1 < N ? br1 : N - 1; }
    const u16* Bg0 = Bt + br0 * K + q0 * 8;
    const u16* Bg1 = Bt + br1 * K + q1 * 8;
    u16* ldsA0 = As + w * 1024;        // bytes: w*2048
    u16* ldsA1 = As + w * 1024 + 512;
    u16* ldsB0 = Bs + w * 1024;
    u16* ldsB1 = Bs + w * 1024 + 512;

    f32x4 acc[4][4];
#pragma unroll
    for (int i = 0; i < 4; i++)
#pragma unroll
        for (int j = 0; j < 4; j++) acc[i][j] = f32x4{0.f, 0.f, 0.f, 0.f};

    for (int k0 = 0; k0 < K; k0 += 32) {
        __syncthreads();               // prior iteration's LDS reads done
        gload16(Ag0, ldsA0);
        gload16(Ag1, ldsA1);
        gload16(Bg0, ldsB0);
        gload16(Bg1, ldsB1);
        __syncthreads();               // drains vmcnt -> staging complete
        bf16x8 af[4], bfr[4];
#pragma unroll
        for (int i = 0; i < 4; i++) {
            const int row = wm * 64 + i * 16 + l16;
            const int qs  = quad ^ ((row >> 1) & 3);
            af[i] = *(const bf16x8*)(&As[row * 32 + qs * 8]);
        }
#pragma unroll
        for (int j = 0; j < 4; j++) {
            const int row = wn * 64 + j * 16 + l16;
            const int qs  = quad ^ ((row >> 1) & 3);
            bfr[j] = *(const bf16x8*)(&Bs[row * 32 + qs * 8]);
        }
#pragma unroll
        for (int i = 0; i < 4; i++)
#pragma unroll
            for (int j = 0; j < 4; j++)
                acc[i][j] = __builtin_amdgcn_mfma_f32_16x16x32_bf16(af[i], bfr[j], acc[i][j], 0, 0, 0);
        Ag0 += 32; Ag1 += 32; Bg0 += 32; Bg1 += 32;
    }

    // epilogue: C/D layout col = lane&15, row = quad*4 + reg
#pragma unroll
    for (int j = 0; j < 4; j++) {
        const int col = (int)n0 + wn * 64 + j * 16 + l16;
        float bv = 0.f;
        if (BIAS) bv = (!NBOUND || col < N) ? b2f(bias[col]) : 0.f;
#pragma unroll
        for (int i = 0; i < 4; i++) {
#pragma unroll
            for (int r = 0; r < 4; r++) {
                const long row = m0 + wm * 64 + i * 16 + quad * 4 + r;
                float v = acc[i][j][r] + bv;
                if (RELU) v = fmaxf(v, 0.f);
                if (RESID) {
                    Cf[row * N + col] = resid[row * N + col] + v;
                } else if (FOUT) {
                    if (!NBOUND || col < N) Cf[row * N + col] = v;
                } else {
                    if (!NBOUND || col < N) Cb[row * N + col] = f2b(v);
                }
            }
        }
    }
}

// ------------------------------- attention ---------------------------------
// wave = one (seq, head); lane = t*2 + half; thread owns 32 of DH=64.
// Online softmax (running m, l; rescale oacc) -> no spill.
__global__ __launch_bounds__(256, 2) void attn_kernel(const u16* __restrict__ qkv,
                                                      u16* __restrict__ o) {
    const int gw   = blockIdx.x * 4 + (threadIdx.x >> 6);   // global wave id
    const int seq  = gw / HH;
    const int h    = gw - seq * HH;
    const int lane = threadIdx.x & 63;
    const int t    = lane >> 1;
    const int half = lane & 1;
    const u16* base = qkv + (size_t)seq * TT * QKVN;
    const int hoff  = h * DHEAD + half * 32;

    float q[32];
    {
        const uint4* qp = (const uint4*)(base + t * QKVN + hoff);
#pragma unroll
        for (int i = 0; i < 4; i++) unpack8(qp[i], q + i * 8);
    }

    float m = -1e30f, l = 0.f;
    float oacc[32];
#pragma unroll
    for (int d = 0; d < 32; d++) oacc[d] = 0.f;

    for (int s = 0; s < TT; s++) {
        const uint4* kp = (const uint4*)(base + s * QKVN + 384 + hoff);
        const uint4* vp = (const uint4*)(base + s * QKVN + 768 + hoff);
        float part = 0.f;
#pragma unroll
        for (int i = 0; i < 4; i++) {
            float kf[8]; unpack8(kp[i], kf);
#pragma unroll
            for (int d = 0; d < 8; d++) part += q[i * 8 + d] * kf[d];
        }
        const float full = part + __shfl_xor(part, 1);
        const float scv  = (s <= t) ? full * 0.125f : -1e30f;   // DH^-0.5
        const float newm  = fmaxf(m, scv);
        const float alpha = __expf(m - newm);
        const float p     = __expf(scv - newm);
#pragma unroll
        for (int i = 0; i < 4; i++) {
            float vf[8]; unpack8(vp[i], vf);
#pragma unroll
            for (int d = 0; d < 8; d++)
                oacc[i * 8 + d] = oacc[i * 8 + d] * alpha + p * vf[d];
        }
        l = l * alpha + p;
        m = newm;
    }
    const float inv = 1.f / l;

    u16* orow = o + ((size_t)seq * TT + t) * CDIM + hoff;
    uint4 st[4];
    unsigned* sw = (unsigned*)st;
#pragma unroll
    for (int j = 0; j < 16; j++)
        sw[j] = (unsigned)f2b(oacc[2 * j] * inv) | ((unsigned)f2b(oacc[2 * j + 1] * inv) << 16);
#pragma unroll
    for (int i = 0; i < 4; i++) ((uint4*)orow)[i] = st[i];
}

// ------------------------------- launcher ----------------------------------
extern "C" void kernel_launch(void* const* d_in, const int* in_sizes, int n_in,
                              void* d_out, int out_size, void* d_ws, size_t ws_size,
                              hipStream_t stream) {
    const int*  idx  = (const int*)d_in[0];
    const void* tok  = d_in[1];
    const void* pos  = d_in[2];
    const void* ln1g = d_in[3];
    const void* ln1b = d_in[4];
    const void* Wq   = d_in[5];
    const void* Wk   = d_in[6];
    const void* Wv   = d_in[7];
    const void* Wo   = d_in[8];
    const void* bo   = d_in[9];
    const void* ln2g = d_in[10];
    const void* ln2b = d_in[11];
    const void* W1   = d_in[12];
    const void* b1   = d_in[13];
    const void* W2   = d_in[14];
    const void* b2   = d_in[15];
    const void* lnfg = d_in[16];
    const void* lnfb = d_in[17];
    const void* Wlm  = d_in[18];
    const void* blm  = d_in[19];

    // ---- workspace layout (adaptive batch chunking) ----
    const size_t wq_b  = (size_t)LLAY * QKVN * CDIM * 2;
    const size_t wo_b  = (size_t)LLAY * CDIM * CDIM * 2;
    const size_t w1_b  = (size_t)LLAY * FFDIM * CDIM * 2;
    const size_t w2_b  = (size_t)LLAY * CDIM * FFDIM * 2;
    const size_t wlm_b = (size_t)VOCAB * CDIM * 2;
    const size_t wts   = wq_b + wo_b + w1_b + w2_b + wlm_b;   // ~21.3 MB

    // pbuf: converted 1-D params, bf16 elements
    const unsigned P_LN1G = 0,      P_LN1B = 2304,  P_BO  = 4608;
    const unsigned P_LN2G = 6912,   P_LN2B = 9216,  P_B1  = 11520;
    const unsigned P_B2   = 20736,  P_LNFG = 23040, P_LNFB = 23424;
    const unsigned P_BLM  = 23808,  P_TOT  = 23888;
    const size_t pbuf_b = ((size_t)P_TOT * 2 + 255) & ~(size_t)255;

    // per-row bytes: x fp32 1536 + h bf16 768 + S (max(qkv+o, u)) 3072 = 5376
    int NC = 32;
    {
        const int cand[6] = {1, 2, 4, 8, 16, 32};
        for (int ci = 0; ci < 6; ci++) {
            size_t rows_c = (size_t)M_TOK / cand[ci];
            size_t need = rows_c * 5376 + wts + pbuf_b + 4096;
            if (need <= ws_size) { NC = cand[ci]; break; }
        }
    }
    const size_t rows = (size_t)M_TOK / NC;
    const int mt = (int)(rows / 128);    // m-tiles; divisible by 8 for all NC

    char* ws = (char*)d_ws;
    size_t off = 0;
    float* x    = (float*)(ws + off); off += rows * CDIM * 4;         // fp32 residual
    u16*   h    = (u16*)(ws + off);   off += rows * CDIM * 2;         // LN out
    char*  S    = ws + off;           off += rows * 3072;             // shared scratch
    u16*   qkv  = (u16*)S;                                            // rows*1152 bf16
    u16*   o    = (u16*)(S + rows * QKVN * 2);                        // rows*384 bf16
    u16*   u    = (u16*)S;                                            // rows*1536 bf16 (qkv,o dead)
    u16* wqkvT  = (u16*)(ws + off);   off += wq_b;
    u16* woT    = (u16*)(ws + off);   off += wo_b;
    u16* w1T    = (u16*)(ws + off);   off += w1_b;
    u16* w2T    = (u16*)(ws + off);   off += w2_b;
    u16* wlmT   = (u16*)(ws + off);   off += wlm_b;
    u16* pbuf   = (u16*)(ws + off);   off += pbuf_b;
    int* flag   = (int*)(ws + off);   off += 256;

    // ---- dtype detect + param convert + weight repack (once per call) ----
    detect_dtype_kernel<<<1, 64, 0, stream>>>(ln1g, flag);

    struct { const void* src; unsigned doff, n; } cv[10] = {
        { ln1g, P_LN1G, 2304 }, { ln1b, P_LN1B, 2304 }, { bo, P_BO, 2304 },
        { ln2g, P_LN2G, 2304 }, { ln2b, P_LN2B, 2304 }, { b1, P_B1, 9216 },
        { b2,   P_B2,   2304 }, { lnfg, P_LNFG, 384 },  { lnfb, P_LNFB, 384 },
        { blm,  P_BLM,  80 },
    };
    for (int i = 0; i < 10; i++)
        cvt_kernel<<<(cv[i].n + 255) / 256, 256, 0, stream>>>(cv[i].src, pbuf + cv[i].doff, cv[i].n, flag);

    {
        unsigned tq = (unsigned)LLAY * QKVN * CDIM;
        pack_qkv_kernel<<<(tq + 255) / 256, 256, 0, stream>>>(Wq, Wk, Wv, wqkvT, flag);
        unsigned t1 = (unsigned)LLAY * CDIM * CDIM;
        transpose_kernel<<<(t1 + 255) / 256, 256, 0, stream>>>(Wo, woT, CDIM, CDIM, t1, flag);
        unsigned t2t = (unsigned)LLAY * CDIM * FFDIM;
        transpose_kernel<<<(t2t + 255) / 256, 256, 0, stream>>>(W1, w1T, CDIM, FFDIM, t2t, flag);
        transpose_kernel<<<(t2t + 255) / 256, 256, 0, stream>>>(W2, w2T, FFDIM, CDIM, t2t, flag);
        unsigned t3 = (unsigned)VOCAB * CDIM;
        transpose_kernel<<<(t3 + 255) / 256, 256, 0, stream>>>(Wlm, wlmT, CDIM, VOCAB, t3, flag);
    }

    // ---- batch-chunked forward ----
    for (int c = 0; c < NC; c++) {
        const size_t r0 = c * rows;            // first token-row of chunk
        embed_kernel<<<(rows * CDIM) / 256, 256, 0, stream>>>(idx, tok, pos, x, (unsigned)r0, flag);

        for (int l = 0; l < LLAY; l++) {
            ln_kernel<<<rows / 4, 256, 0, stream>>>(x, pbuf + P_LN1G + l * CDIM, pbuf + P_LN1B + l * CDIM, h);
            gemm_kernel<false, false, false, false, false><<<mt * (QKVN / 128), 256, 0, stream>>>(
                h, wqkvT + (size_t)l * QKVN * CDIM, nullptr, nullptr, qkv, nullptr, QKVN, CDIM, QKVN / 128);
            attn_kernel<<<(rows / TT) * HH / 4, 256, 0, stream>>>(qkv, o);
            gemm_kernel<true, false, true, false, false><<<mt * (CDIM / 128), 256, 0, stream>>>(
                o, woT + (size_t)l * CDIM * CDIM, pbuf + P_BO + l * CDIM, x, nullptr, x, CDIM, CDIM, CDIM / 128);
            ln_kernel<<<rows / 4, 256, 0, stream>>>(x, pbuf + P_LN2G + l * CDIM, pbuf + P_LN2B + l * CDIM, h);
            gemm_kernel<true, true, false, false, false><<<mt * (FFDIM / 128), 256, 0, stream>>>(
                h, w1T + (size_t)l * FFDIM * CDIM, pbuf + P_B1 + l * FFDIM, nullptr, u, nullptr, FFDIM, CDIM, FFDIM / 128);
            gemm_kernel<true, false, true, false, false><<<mt * (CDIM / 128), 256, 0, stream>>>(
                u, w2T + (size_t)l * CDIM * FFDIM, pbuf + P_B2 + l * CDIM, x, nullptr, x, CDIM, FFDIM, CDIM / 128);
        }

        ln_kernel<<<rows / 4, 256, 0, stream>>>(x, pbuf + P_LNFG, pbuf + P_LNFB, h);
        gemm_kernel<true, false, false, true, true><<<mt, 256, 0, stream>>>(
            h, wlmT, pbuf + P_BLM, nullptr, nullptr, (float*)d_out + r0 * VOCAB, VOCAB, CDIM, 1);
    }
}